// Round 5
// baseline (317.622 us; speedup 1.0000x reference)
//
#include <hip/hip_runtime.h>
#include <math.h>

// Problem constants
#define Bb 8
#define Ss 4096
#define Hh 1024
#define Rr 128
#define Nn 256
#define Mm (Bb*Ss)          // 32768 rows
#define LCH 128             // scan chunk length (== proj m-tile == G4 m-tile!)
#define NCHK (Ss/LCH)       // 32 chunks

typedef __attribute__((ext_vector_type(8))) short bf16x8;   // 8 bf16 = 4 VGPRs
typedef __attribute__((ext_vector_type(4))) float f32x4;

__device__ __forceinline__ float sigmoidf_(float x) { return 1.0f / (1.0f + expf(-x)); }
__device__ __forceinline__ float softplusf_(float x) { return log1pf(expf(x)); }

__device__ __forceinline__ unsigned short f2b(float f) {
    union { float f; unsigned int u; } v; v.f = f;
    return (unsigned short)((v.u + 0x7fffu + ((v.u >> 16) & 1u)) >> 16);
}
__device__ __forceinline__ float b2f(unsigned short h) {
    union { unsigned int u; float f; } v; v.u = ((unsigned int)h) << 16;
    return v.f;
}

__device__ __forceinline__ void gl_lds16(const void* g, void* l) {
    __builtin_amdgcn_global_load_lds(
        (const __attribute__((address_space(1))) void*)g,
        (__attribute__((address_space(3))) void*)l, 16, 0, 0);
}

// LDS tile swizzle (all [rows][32]-bf16 tiles, 64B rows):
//   physical 16B slot = logical slot ^ ((row>>1)&3)
// Staged tiles pre-swizzle the per-lane GLOBAL source k-offset (LDS dest of
// global_load_lds stays linear); reads apply the same XOR. Verified R1.
// 2-phase double-buffer schedule per T3-minimum recipe (verified R2).
// R4: scan_g4 GEMM is barrier-free (B direct global->reg from L2-resident
// out_proj; ys read-only after replay). u,c interleaved into UC (u|c<<16).

// -------------------------------------------------------------------------
// cast weights to bf16 (tiny, one pass)
// -------------------------------------------------------------------------
__global__ __launch_bounds__(256)
void cast_w(const float* __restrict__ s0, const float* __restrict__ s1,
            const float* __restrict__ s2, const float* __restrict__ s3,
            const float* __restrict__ s4,
            unsigned short* __restrict__ d0, unsigned short* __restrict__ d1,
            unsigned short* __restrict__ d2, unsigned short* __restrict__ d3,
            unsigned short* __restrict__ d4)
{
    const int i = blockIdx.x * 256 + threadIdx.x;
    if (i < 131072)      d0[i] = f2b(s0[i]);
    else if (i < 163840) d1[i - 131072] = f2b(s1[i - 131072]);
    else if (i < 196608) d2[i - 163840] = f2b(s2[i - 163840]);
    else if (i < 229376) d3[i - 196608] = f2b(s3[i - 196608]);
    else                 d4[i - 229376] = f2b(s4[i - 229376]);
}

// -------------------------------------------------------------------------
// G1: z[M,128] = x[M,1024](fp32) * in_basis[128,1024](bf16)^T, z bf16.
// 64x128 tile, BK=32, 4 waves, wave 32x64. Double-buffered 2-phase schedule;
// x loads issued early (T14 split: load next -> MFMA -> cvt+ds_write next).
// -------------------------------------------------------------------------
__global__ __launch_bounds__(256)
void g1_fused(const float* __restrict__ X, const unsigned short* __restrict__ IB,
              unsigned short* __restrict__ Z)
{
    __shared__ __align__(16) unsigned short As[2][64 * 32];    // 2 x 4 KB
    __shared__ __align__(16) unsigned short Bs[2][128 * 32];   // 2 x 8 KB
    const int tid = threadIdx.x;
    const int wave = tid >> 6, lane = tid & 63;
    const int m0 = blockIdx.x * 64;
    const int wm = (wave & 1) * 32, wn = (wave >> 1) * 64;
    const int quad = lane >> 4, lm = lane & 15;
    const int srow = lane >> 2;            // 0..15
    const int skoff = (((lane & 3) ^ ((srow >> 1) & 3)) << 3);   // pre-swizzled src
    const int qsw = ((quad ^ ((lm >> 1) & 3)) << 3);             // swizzled read
    const int arow = tid >> 3;             // 0..31 (row within 32-region)
    const int akf = (tid & 7) * 4;         // fp32 elems 0..28
    const int awoff = ((((tid & 7) >> 1) ^ ((arow >> 1) & 3)) << 3) + (tid & 1) * 4;

    f32x4 acc[2][4] = {};
    float4 va[2];

    // prologue: stage k0=0 into buffer 0
#pragma unroll
    for (int q = 0; q < 2; ++q)
        va[q] = *(const float4*)(X + (size_t)(m0 + q * 32 + arow) * Hh + akf);
    gl_lds16(IB + (size_t)(2 * wave * 16 + srow) * Hh + skoff, &Bs[0][wave * 1024]);
    gl_lds16(IB + (size_t)((2 * wave + 1) * 16 + srow) * Hh + skoff, &Bs[0][wave * 1024 + 512]);
#pragma unroll
    for (int q = 0; q < 2; ++q) {
        uint2 o;
        o.x = (unsigned)f2b(va[q].x) | ((unsigned)f2b(va[q].y) << 16);
        o.y = (unsigned)f2b(va[q].z) | ((unsigned)f2b(va[q].w) << 16);
        *(uint2*)&As[0][(q * 32 + arow) * 32 + awoff] = o;
    }
    __syncthreads();

    int cur = 0;
    for (int k0 = 0; k0 < Hh; k0 += 32) {
        const int nxt = cur ^ 1;
        const bool more = (k0 + 32) < Hh;
        if (more) {
            // issue next-phase staging first: B async -> LDS, A -> regs
            gl_lds16(IB + (size_t)(2 * wave * 16 + srow) * Hh + k0 + 32 + skoff, &Bs[nxt][wave * 1024]);
            gl_lds16(IB + (size_t)((2 * wave + 1) * 16 + srow) * Hh + k0 + 32 + skoff, &Bs[nxt][wave * 1024 + 512]);
#pragma unroll
            for (int q = 0; q < 2; ++q)
                va[q] = *(const float4*)(X + (size_t)(m0 + q * 32 + arow) * Hh + k0 + 32 + akf);
        }
        bf16x8 af[2], bfv[4];
#pragma unroll
        for (int i = 0; i < 2; ++i)
            af[i] = *(const bf16x8*)&As[cur][(wm + i * 16 + lm) * 32 + qsw];
#pragma unroll
        for (int j = 0; j < 4; ++j)
            bfv[j] = *(const bf16x8*)&Bs[cur][(wn + j * 16 + lm) * 32 + qsw];
#pragma unroll
        for (int i = 0; i < 2; ++i)
#pragma unroll
            for (int j = 0; j < 4; ++j)
                acc[i][j] = __builtin_amdgcn_mfma_f32_16x16x32_bf16(af[i], bfv[j], acc[i][j], 0, 0, 0);
        if (more) {
#pragma unroll
            for (int q = 0; q < 2; ++q) {
                uint2 o;
                o.x = (unsigned)f2b(va[q].x) | ((unsigned)f2b(va[q].y) << 16);
                o.y = (unsigned)f2b(va[q].z) | ((unsigned)f2b(va[q].w) << 16);
                *(uint2*)&As[nxt][(q * 32 + arow) * 32 + awoff] = o;
            }
        }
        __syncthreads();
        cur = nxt;
    }

#pragma unroll
    for (int i = 0; i < 2; ++i) {
        const int rbase = m0 + wm + i * 16 + quad * 4;
#pragma unroll
        for (int j = 0; j < 4; ++j) {
            const int col = wn + j * 16 + lm;
#pragma unroll
            for (int r = 0; r < 4; ++r)
                Z[(size_t)(rbase + r) * Rr + col] = f2b(acc[i][j][r]);
        }
    }
}

// -------------------------------------------------------------------------
// G2 staging helper: one BK=32 subtile of z/K/Q/V into one LDS buffer.
// Per-buffer layout: zs +0 (8 KB), ks +8192, qs +12288, vs +16384 (20480 B).
// -------------------------------------------------------------------------
__device__ __forceinline__ void proj_stage(const unsigned short* Zm, const unsigned short* Kw,
                                           const unsigned short* Qw, const unsigned short* Vw,
                                           char* bb, int m0, int n0, int k0,
                                           int wave, int srow, int skoff)
{
    unsigned short* zs = (unsigned short*)bb;
    unsigned short* ks = (unsigned short*)(bb + 8192);
    unsigned short* qs = (unsigned short*)(bb + 12288);
    unsigned short* vs = (unsigned short*)(bb + 16384);
    gl_lds16(Zm + (size_t)(m0 + 2 * wave * 16 + srow) * Rr + k0 + skoff, &zs[wave * 1024]);
    gl_lds16(Zm + (size_t)(m0 + (2 * wave + 1) * 16 + srow) * Rr + k0 + skoff, &zs[wave * 1024 + 512]);
    gl_lds16(Kw + (size_t)(n0 + wave * 16 + srow) * Rr + k0 + skoff, &ks[wave * 512]);
    gl_lds16(Qw + (size_t)(n0 + wave * 16 + srow) * Rr + k0 + skoff, &qs[wave * 512]);
    gl_lds16(Vw + (size_t)(n0 + wave * 16 + srow) * Rr + k0 + skoff, &vs[wave * 512]);
}

// -------------------------------------------------------------------------
// G2: from z[M,128] bf16: b=z*Kw^T, c=z*Qw^T, v=z*Vw^T; u=softplus(dl)*b*v.
// Block tile 128m x 64n, wave 64x32. Double-buffered 2-phase (4 k-phases).
// Epilogue computes P[chunk,n] and writes interleaved UC = u | c<<16.
// -------------------------------------------------------------------------
__global__ __launch_bounds__(256)
void proj_mfma(const unsigned short* __restrict__ Zm, const unsigned short* __restrict__ Kw,
               const unsigned short* __restrict__ Qw, const unsigned short* __restrict__ Vw,
               const float* __restrict__ delta_log, const float* __restrict__ a_logit,
               unsigned int* __restrict__ UC, float* __restrict__ Pout)
{
    __shared__ __align__(16) char smem[41984];      // 2x20480 tiles + 1 KB pcomb
    float* uL = (float*)smem;                       // 128 x 66 fp32 (union, post-loop)
    float* pcomb = (float*)(smem + 40960);          // 4 x 64 fp32

    const int tid = threadIdx.x;
    const int wave = tid >> 6, lane = tid & 63;
    const int m0 = blockIdx.x * 128, n0 = blockIdx.y * 64;
    const int wm = (wave & 1) * 64, wn = (wave >> 1) * 32;
    const int quad = lane >> 4, lm = lane & 15;
    const int srow = lane >> 2;
    const int skoff = (((lane & 3) ^ ((srow >> 1) & 3)) << 3);   // pre-swizzled src
    const int qsw = ((quad ^ ((lm >> 1) & 3)) << 3);             // swizzled read

    f32x4 aB[4][2] = {}, aC[4][2] = {}, aV[4][2] = {};

    proj_stage(Zm, Kw, Qw, Vw, smem, m0, n0, 0, wave, srow, skoff);
    __syncthreads();

    int cur = 0;
    for (int p = 0; p < 4; ++p) {                   // k0 = p*32
        if (p < 3)
            proj_stage(Zm, Kw, Qw, Vw, smem + (cur ^ 1) * 20480, m0, n0,
                       (p + 1) * 32, wave, srow, skoff);
        const unsigned short* zsc = (const unsigned short*)(smem + cur * 20480);
        const unsigned short* ksc = zsc + 4096;
        const unsigned short* qsc = zsc + 6144;
        const unsigned short* vsc = zsc + 8192;
        bf16x8 zf[4], wf[2];
#pragma unroll
        for (int i = 0; i < 4; ++i)
            zf[i] = *(const bf16x8*)&zsc[(wm + i * 16 + lm) * 32 + qsw];
#pragma unroll
        for (int j = 0; j < 2; ++j)
            wf[j] = *(const bf16x8*)&ksc[(wn + j * 16 + lm) * 32 + qsw];
#pragma unroll
        for (int i = 0; i < 4; ++i)
#pragma unroll
            for (int j = 0; j < 2; ++j)
                aB[i][j] = __builtin_amdgcn_mfma_f32_16x16x32_bf16(zf[i], wf[j], aB[i][j], 0, 0, 0);
#pragma unroll
        for (int j = 0; j < 2; ++j)
            wf[j] = *(const bf16x8*)&qsc[(wn + j * 16 + lm) * 32 + qsw];
#pragma unroll
        for (int i = 0; i < 4; ++i)
#pragma unroll
            for (int j = 0; j < 2; ++j)
                aC[i][j] = __builtin_amdgcn_mfma_f32_16x16x32_bf16(zf[i], wf[j], aC[i][j], 0, 0, 0);
#pragma unroll
        for (int j = 0; j < 2; ++j)
            wf[j] = *(const bf16x8*)&vsc[(wn + j * 16 + lm) * 32 + qsw];
#pragma unroll
        for (int i = 0; i < 4; ++i)
#pragma unroll
            for (int j = 0; j < 2; ++j)
                aV[i][j] = __builtin_amdgcn_mfma_f32_16x16x32_bf16(zf[i], wf[j], aV[i][j], 0, 0, 0);
        __syncthreads();
        cur ^= 1;
    }

    float dl[2];
#pragma unroll
    for (int j = 0; j < 2; ++j)
        dl[j] = softplusf_(delta_log[n0 + wn + j * 16 + lm]);

    // epilogue: write UC = u | c<<16 (one 4B store) + u fp32 to LDS for P
#pragma unroll
    for (int i = 0; i < 4; ++i) {
        const int lrow = wm + i * 16 + quad * 4;
        const int rbase = m0 + lrow;
#pragma unroll
        for (int j = 0; j < 2; ++j) {
            const int col = wn + j * 16 + lm;        // 0..63 within block
            const int gcol = n0 + col;
#pragma unroll
            for (int r = 0; r < 4; ++r) {
                const float uval = dl[j] * aB[i][j][r] * aV[i][j][r];
                const size_t idx = (size_t)(rbase + r) * Nn + gcol;
                UC[idx] = (unsigned)f2b(uval) | ((unsigned)f2b(aC[i][j][r]) << 16);
                uL[(lrow + r) * 66 + col] = uval;
            }
        }
    }
    __syncthreads();

    // chunk-local scan contribution P: 4 segments of 32 rows/col
    const int colp = tid & 63, seg = tid >> 6;
    const float a = sigmoidf_(a_logit[n0 + colp]);
    float l = 0.0f;
#pragma unroll 8
    for (int r = 0; r < 32; ++r)
        l = fmaf(a, l, uL[(seg * 32 + r) * 66 + colp]);
    pcomb[seg * 64 + colp] = l;
    __syncthreads();
    if (tid < 64) {
        float a32 = a;
#pragma unroll
        for (int i = 0; i < 5; ++i) a32 *= a32;      // a^32
        const float Pv = ((pcomb[tid] * a32 + pcomb[64 + tid]) * a32
                          + pcomb[128 + tid]) * a32 + pcomb[192 + tid];
        Pout[(size_t)blockIdx.x * Nn + n0 + tid] = Pv;
    }
}

// -------------------------------------------------------------------------
// Scan pass B: sequential over 32 chunks (fully unrolled); entry states + final.
// -------------------------------------------------------------------------
__global__ __launch_bounds__(256)
void scan_mid(const float* __restrict__ P, const float* __restrict__ state0,
              const float* __restrict__ a_logit,
              float* __restrict__ start, float* __restrict__ final_state)
{
    const int g = blockIdx.x * blockDim.x + threadIdx.x;
    const int n = g & (Nn - 1);
    const int b = g >> 8;
    const float a = sigmoidf_(a_logit[n]);
    float aL = a;
#pragma unroll
    for (int i = 0; i < 7; ++i) aL *= aL;   // a^128
    float s = state0[g];
#pragma unroll
    for (int ch = 0; ch < NCHK; ++ch) {
        const size_t idx = ((size_t)(b * NCHK + ch)) * Nn + n;
        start[idx] = s;
        s = fmaf(aL, s, P[idx]);
    }
    final_state[g] = s;
}

// -------------------------------------------------------------------------
// FUSED scan replay + G4 (R4: barrier-free GEMM phase).
// grid dim3(2, 256): by = chunk (m-tile), bx = 512-col output half.
// 512 threads (8 waves), LDS 64 KB (ys only) -> 2 blocks/CU, 16 waves/CU.
//   Phase 1: waves 0-1 (tid<128) replay the chunk scan from entry states
//            (one uint2 load per thread/step from interleaved UC), writing
//            ys bf16 into the 64 KB XOR-swizzled LDS tile. One barrier.
//   Phase 2: out[128 rows, 512 cols] = ys * OB^T with NO LDS staging and NO
//            barriers: B fragments load directly global->reg (out_proj is
//            512 KB bf16 -> L2-resident everywhere); A from swizzled ys.
//            4 n-subtiles x 8 k-phases x {2 glb loads + 4 ds_read + 8 MFMA}.
//            16 desynchronized waves/CU hide all latency (m114 regime).
// -------------------------------------------------------------------------
__global__ __launch_bounds__(512, 4)
void scan_g4_fused(const unsigned int* __restrict__ UC,
                   const float* __restrict__ start, const float* __restrict__ a_logit,
                   const unsigned short* __restrict__ OB, float* __restrict__ Out)
{
    __shared__ __align__(16) unsigned short ys[128 * 256];   // 64 KB, swizzled
    const int tid = threadIdx.x;
    const int wave = tid >> 6, lane = tid & 63;
    const int hbase = blockIdx.x * 512;      // output column half
    const int m0 = blockIdx.y * 128;
    const int bidx = m0 >> 12;               // batch = m0 / Ss
    const int ch = (m0 & (Ss - 1)) >> 7;     // within-batch chunk
    const int quad = lane >> 4, lm = lane & 15;

    // ---- phase 1: scan replay into LDS (waves 0-1)
    if (tid < 128) {
        const int n = tid * 2;
        const float a0 = sigmoidf_(a_logit[n]);
        const float a1 = sigmoidf_(a_logit[n + 1]);
        const size_t sb = ((size_t)(bidx * NCHK + ch)) * Nn + n;
        float s0 = start[sb], s1 = start[sb + 1];
        size_t gb = ((size_t)m0) * Nn + n;   // index into UC (uint units)
        const int slot = n >> 3;             // 16B-slot of this col pair
        const int e = n & 7;                 // even -> 4B-aligned LDS store
#pragma unroll 8
        for (int t = 0; t < LCH; ++t) {
            const uint2 w = *(const uint2*)(UC + gb);
            s0 = fmaf(a0, s0, b2f((unsigned short)(w.x & 0xffffu)));
            s1 = fmaf(a1, s1, b2f((unsigned short)(w.y & 0xffffu)));
            const float y0 = b2f((unsigned short)(w.x >> 16)) * s0;
            const float y1 = b2f((unsigned short)(w.y >> 16)) * s1;
            *(unsigned*)&ys[t * 256 + (((slot ^ (t & 7)) << 3) + e)] =
                (unsigned)f2b(y0) | ((unsigned)f2b(y1) << 16);
            gb += Nn;
        }
    }
    __syncthreads();

    // ---- phase 2: barrier-free GEMM out[m0..+128, hbase..+512] = ys * OB^T
    // 8 waves as 2m x 4n over a 128x128 n-subtile; 4 subtiles.
    const int wm = (wave & 1) * 64, wn = (wave >> 1) * 32;

    for (int sub = 0; sub < 4; ++sub) {
        const int n0g = hbase + sub * 128;
        f32x4 acc[4][2] = {};
#pragma unroll 2
        for (int p = 0; p < 8; ++p) {
            const int k0 = p * 32;
            bf16x8 bfv[2], af[4];
#pragma unroll
            for (int j = 0; j < 2; ++j)
                bfv[j] = *(const bf16x8*)(OB + (size_t)(n0g + wn + j * 16 + lm) * Nn + k0 + quad * 8);
            const int c8 = p * 4 + quad;     // logical 16B-slot in ys row
#pragma unroll
            for (int i = 0; i < 4; ++i) {
                const int r = wm + i * 16 + lm;
                af[i] = *(const bf16x8*)&ys[r * 256 + ((c8 ^ (r & 7)) << 3)];
            }
#pragma unroll
            for (int i = 0; i < 4; ++i)
#pragma unroll
                for (int j = 0; j < 2; ++j)
                    acc[i][j] = __builtin_amdgcn_mfma_f32_16x16x32_bf16(af[i], bfv[j], acc[i][j], 0, 0, 0);
        }
#pragma unroll
        for (int i = 0; i < 4; ++i) {
            const int rbase = m0 + wm + i * 16 + quad * 4;
#pragma unroll
            for (int j = 0; j < 2; ++j) {
                const int col = n0g + wn + j * 16 + lm;
#pragma unroll
                for (int r = 0; r < 4; ++r)
                    Out[(size_t)(rbase + r) * Hh + col] = acc[i][j][r];
            }
        }
    }
}

// -------------------------------------------------------------------------
extern "C" void kernel_launch(void* const* d_in, const int* in_sizes, int n_in,
                              void* d_out, int out_size, void* d_ws, size_t ws_size,
                              hipStream_t stream)
{
    const float* x         = (const float*)d_in[0];
    const float* state0    = (const float*)d_in[1];
    const float* in_basis  = (const float*)d_in[2];
    const float* q_select  = (const float*)d_in[3];
    const float* k_select  = (const float*)d_in[4];
    const float* v_input   = (const float*)d_in[5];
    const float* out_proj  = (const float*)d_in[6];
    const float* a_logit   = (const float*)d_in[7];
    const float* delta_log = (const float*)d_in[8];

    float* out = (float*)d_out;
    float* final_state = out + (size_t)Mm * Hh;

    // workspace carve (~43.5 MB)
    char* ws = (char*)d_ws;
    unsigned int* uc   = (unsigned int*)ws;                      // 32 MB (u|c<<16)
    unsigned short* zb = (unsigned short*)(ws + 33554432);       // 8 MB
    unsigned short* ib = (unsigned short*)(ws + 41943040);       // 256 KB
    unsigned short* kb = (unsigned short*)(ws + 42205184);       // 64 KB
    unsigned short* qb = (unsigned short*)(ws + 42270720);       // 64 KB
    unsigned short* vb = (unsigned short*)(ws + 42336256);       // 64 KB
    unsigned short* ob = (unsigned short*)(ws + 42401792);       // 512 KB
    float* P  = (float*)(ws + 42926080);                         // 256 KB
    float* st = (float*)(ws + 43188224);                         // 256 KB

    cast_w<<<491520 / 256, 256, 0, stream>>>(in_basis, k_select, q_select, v_input, out_proj,
                                             ib, kb, qb, vb, ob);

    // G1: z = x * in_basis^T (fp32 x read directly, bf16 out)
    g1_fused<<<Mm / 64, 256, 0, stream>>>(x, ib, zb);

    // G2: uc (+ chunk contributions P) from z
    proj_mfma<<<dim3(Mm / 128, Nn / 64), 256, 0, stream>>>(zb, kb, qb, vb,
                                                           delta_log, a_logit, uc, P);

    // chunk-boundary scan (entry states per 128-chunk)
    scan_mid<<<(Bb * Nn) / 256, 256, 0, stream>>>(P, state0, a_logit, st, final_state);

    // fused: replay chunk scan in LDS + out = ys * out_proj^T (barrier-free GEMM)
    scan_g4_fused<<<dim3(2, Mm / 128), 512, 0, stream>>>(uc, st, a_logit, ob, out);
}

// Round 6
// 306.366 us; speedup vs baseline: 1.0367x; 1.0367x over previous
//
#include <hip/hip_runtime.h>
#include <math.h>

// Problem constants
#define Bb 8
#define Ss 4096
#define Hh 1024
#define Rr 128
#define Nn 256
#define Mm (Bb*Ss)          // 32768 rows
#define LCH 128             // scan chunk length (== proj m-tile == G4 m-tile!)
#define NCHK (Ss/LCH)       // 32 chunks

typedef __attribute__((ext_vector_type(8))) short bf16x8;   // 8 bf16 = 4 VGPRs
typedef __attribute__((ext_vector_type(4))) float f32x4;

__device__ __forceinline__ float sigmoidf_(float x) { return 1.0f / (1.0f + expf(-x)); }
__device__ __forceinline__ float softplusf_(float x) { return log1pf(expf(x)); }

__device__ __forceinline__ unsigned short f2b(float f) {
    union { float f; unsigned int u; } v; v.f = f;
    return (unsigned short)((v.u + 0x7fffu + ((v.u >> 16) & 1u)) >> 16);
}
__device__ __forceinline__ float b2f(unsigned short h) {
    union { unsigned int u; float f; } v; v.u = ((unsigned int)h) << 16;
    return v.f;
}

__device__ __forceinline__ void gl_lds16(const void* g, void* l) {
    __builtin_amdgcn_global_load_lds(
        (const __attribute__((address_space(1))) void*)g,
        (__attribute__((address_space(3))) void*)l, 16, 0, 0);
}

// LDS tile swizzle (all [rows][32]-bf16 tiles, 64B rows):
//   physical 16B slot = logical slot ^ ((row>>1)&3)
// Staged tiles pre-swizzle the per-lane GLOBAL source k-offset (LDS dest of
// global_load_lds stays linear); reads apply the same XOR. Verified R1.
// 2-phase double-buffer schedule per T3-minimum recipe (verified R2).
// R4 lesson: do NOT replace staged B with direct per-lane global loads --
// the gl_lds pipeline beats "barrier-free + blocking loads" (+9us regression).
// R5: R3's staged GEMM restored; UC interleave (u|c<<16) kept.

// -------------------------------------------------------------------------
// cast weights to bf16 (tiny, one pass)
// -------------------------------------------------------------------------
__global__ __launch_bounds__(256)
void cast_w(const float* __restrict__ s0, const float* __restrict__ s1,
            const float* __restrict__ s2, const float* __restrict__ s3,
            const float* __restrict__ s4,
            unsigned short* __restrict__ d0, unsigned short* __restrict__ d1,
            unsigned short* __restrict__ d2, unsigned short* __restrict__ d3,
            unsigned short* __restrict__ d4)
{
    const int i = blockIdx.x * 256 + threadIdx.x;
    if (i < 131072)      d0[i] = f2b(s0[i]);
    else if (i < 163840) d1[i - 131072] = f2b(s1[i - 131072]);
    else if (i < 196608) d2[i - 163840] = f2b(s2[i - 163840]);
    else if (i < 229376) d3[i - 196608] = f2b(s3[i - 196608]);
    else                 d4[i - 229376] = f2b(s4[i - 229376]);
}

// -------------------------------------------------------------------------
// G1: z[M,128] = x[M,1024](fp32) * in_basis[128,1024](bf16)^T, z bf16.
// 64x128 tile, BK=32, 4 waves, wave 32x64. Double-buffered 2-phase schedule;
// x loads issued early (T14 split: load next -> MFMA -> cvt+ds_write next).
// -------------------------------------------------------------------------
__global__ __launch_bounds__(256)
void g1_fused(const float* __restrict__ X, const unsigned short* __restrict__ IB,
              unsigned short* __restrict__ Z)
{
    __shared__ __align__(16) unsigned short As[2][64 * 32];    // 2 x 4 KB
    __shared__ __align__(16) unsigned short Bs[2][128 * 32];   // 2 x 8 KB
    const int tid = threadIdx.x;
    const int wave = tid >> 6, lane = tid & 63;
    const int m0 = blockIdx.x * 64;
    const int wm = (wave & 1) * 32, wn = (wave >> 1) * 64;
    const int quad = lane >> 4, lm = lane & 15;
    const int srow = lane >> 2;            // 0..15
    const int skoff = (((lane & 3) ^ ((srow >> 1) & 3)) << 3);   // pre-swizzled src
    const int qsw = ((quad ^ ((lm >> 1) & 3)) << 3);             // swizzled read
    const int arow = tid >> 3;             // 0..31 (row within 32-region)
    const int akf = (tid & 7) * 4;         // fp32 elems 0..28
    const int awoff = ((((tid & 7) >> 1) ^ ((arow >> 1) & 3)) << 3) + (tid & 1) * 4;

    f32x4 acc[2][4] = {};
    float4 va[2];

    // prologue: stage k0=0 into buffer 0
#pragma unroll
    for (int q = 0; q < 2; ++q)
        va[q] = *(const float4*)(X + (size_t)(m0 + q * 32 + arow) * Hh + akf);
    gl_lds16(IB + (size_t)(2 * wave * 16 + srow) * Hh + skoff, &Bs[0][wave * 1024]);
    gl_lds16(IB + (size_t)((2 * wave + 1) * 16 + srow) * Hh + skoff, &Bs[0][wave * 1024 + 512]);
#pragma unroll
    for (int q = 0; q < 2; ++q) {
        uint2 o;
        o.x = (unsigned)f2b(va[q].x) | ((unsigned)f2b(va[q].y) << 16);
        o.y = (unsigned)f2b(va[q].z) | ((unsigned)f2b(va[q].w) << 16);
        *(uint2*)&As[0][(q * 32 + arow) * 32 + awoff] = o;
    }
    __syncthreads();

    int cur = 0;
    for (int k0 = 0; k0 < Hh; k0 += 32) {
        const int nxt = cur ^ 1;
        const bool more = (k0 + 32) < Hh;
        if (more) {
            // issue next-phase staging first: B async -> LDS, A -> regs
            gl_lds16(IB + (size_t)(2 * wave * 16 + srow) * Hh + k0 + 32 + skoff, &Bs[nxt][wave * 1024]);
            gl_lds16(IB + (size_t)((2 * wave + 1) * 16 + srow) * Hh + k0 + 32 + skoff, &Bs[nxt][wave * 1024 + 512]);
#pragma unroll
            for (int q = 0; q < 2; ++q)
                va[q] = *(const float4*)(X + (size_t)(m0 + q * 32 + arow) * Hh + k0 + 32 + akf);
        }
        bf16x8 af[2], bfv[4];
#pragma unroll
        for (int i = 0; i < 2; ++i)
            af[i] = *(const bf16x8*)&As[cur][(wm + i * 16 + lm) * 32 + qsw];
#pragma unroll
        for (int j = 0; j < 4; ++j)
            bfv[j] = *(const bf16x8*)&Bs[cur][(wn + j * 16 + lm) * 32 + qsw];
#pragma unroll
        for (int i = 0; i < 2; ++i)
#pragma unroll
            for (int j = 0; j < 4; ++j)
                acc[i][j] = __builtin_amdgcn_mfma_f32_16x16x32_bf16(af[i], bfv[j], acc[i][j], 0, 0, 0);
        if (more) {
#pragma unroll
            for (int q = 0; q < 2; ++q) {
                uint2 o;
                o.x = (unsigned)f2b(va[q].x) | ((unsigned)f2b(va[q].y) << 16);
                o.y = (unsigned)f2b(va[q].z) | ((unsigned)f2b(va[q].w) << 16);
                *(uint2*)&As[nxt][(q * 32 + arow) * 32 + awoff] = o;
            }
        }
        __syncthreads();
        cur = nxt;
    }

#pragma unroll
    for (int i = 0; i < 2; ++i) {
        const int rbase = m0 + wm + i * 16 + quad * 4;
#pragma unroll
        for (int j = 0; j < 4; ++j) {
            const int col = wn + j * 16 + lm;
#pragma unroll
            for (int r = 0; r < 4; ++r)
                Z[(size_t)(rbase + r) * Rr + col] = f2b(acc[i][j][r]);
        }
    }
}

// -------------------------------------------------------------------------
// G2 staging helper: one BK=32 subtile of z/K/Q/V into one LDS buffer.
// Per-buffer layout: zs +0 (8 KB), ks +8192, qs +12288, vs +16384 (20480 B).
// -------------------------------------------------------------------------
__device__ __forceinline__ void proj_stage(const unsigned short* Zm, const unsigned short* Kw,
                                           const unsigned short* Qw, const unsigned short* Vw,
                                           char* bb, int m0, int n0, int k0,
                                           int wave, int srow, int skoff)
{
    unsigned short* zs = (unsigned short*)bb;
    unsigned short* ks = (unsigned short*)(bb + 8192);
    unsigned short* qs = (unsigned short*)(bb + 12288);
    unsigned short* vs = (unsigned short*)(bb + 16384);
    gl_lds16(Zm + (size_t)(m0 + 2 * wave * 16 + srow) * Rr + k0 + skoff, &zs[wave * 1024]);
    gl_lds16(Zm + (size_t)(m0 + (2 * wave + 1) * 16 + srow) * Rr + k0 + skoff, &zs[wave * 1024 + 512]);
    gl_lds16(Kw + (size_t)(n0 + wave * 16 + srow) * Rr + k0 + skoff, &ks[wave * 512]);
    gl_lds16(Qw + (size_t)(n0 + wave * 16 + srow) * Rr + k0 + skoff, &qs[wave * 512]);
    gl_lds16(Vw + (size_t)(n0 + wave * 16 + srow) * Rr + k0 + skoff, &vs[wave * 512]);
}

// -------------------------------------------------------------------------
// G2: from z[M,128] bf16: b=z*Kw^T, c=z*Qw^T, v=z*Vw^T; u=softplus(dl)*b*v.
// Block tile 128m x 64n, wave 64x32. Double-buffered 2-phase (4 k-phases).
// Epilogue computes P[chunk,n] and writes interleaved UC = u | c<<16.
// -------------------------------------------------------------------------
__global__ __launch_bounds__(256)
void proj_mfma(const unsigned short* __restrict__ Zm, const unsigned short* __restrict__ Kw,
               const unsigned short* __restrict__ Qw, const unsigned short* __restrict__ Vw,
               const float* __restrict__ delta_log, const float* __restrict__ a_logit,
               unsigned int* __restrict__ UC, float* __restrict__ Pout)
{
    __shared__ __align__(16) char smem[41984];      // 2x20480 tiles + 1 KB pcomb
    float* uL = (float*)smem;                       // 128 x 66 fp32 (union, post-loop)
    float* pcomb = (float*)(smem + 40960);          // 4 x 64 fp32

    const int tid = threadIdx.x;
    const int wave = tid >> 6, lane = tid & 63;
    const int m0 = blockIdx.x * 128, n0 = blockIdx.y * 64;
    const int wm = (wave & 1) * 64, wn = (wave >> 1) * 32;
    const int quad = lane >> 4, lm = lane & 15;
    const int srow = lane >> 2;
    const int skoff = (((lane & 3) ^ ((srow >> 1) & 3)) << 3);   // pre-swizzled src
    const int qsw = ((quad ^ ((lm >> 1) & 3)) << 3);             // swizzled read

    f32x4 aB[4][2] = {}, aC[4][2] = {}, aV[4][2] = {};

    proj_stage(Zm, Kw, Qw, Vw, smem, m0, n0, 0, wave, srow, skoff);
    __syncthreads();

    int cur = 0;
    for (int p = 0; p < 4; ++p) {                   // k0 = p*32
        if (p < 3)
            proj_stage(Zm, Kw, Qw, Vw, smem + (cur ^ 1) * 20480, m0, n0,
                       (p + 1) * 32, wave, srow, skoff);
        const unsigned short* zsc = (const unsigned short*)(smem + cur * 20480);
        const unsigned short* ksc = zsc + 4096;
        const unsigned short* qsc = zsc + 6144;
        const unsigned short* vsc = zsc + 8192;
        bf16x8 zf[4], wf[2];
#pragma unroll
        for (int i = 0; i < 4; ++i)
            zf[i] = *(const bf16x8*)&zsc[(wm + i * 16 + lm) * 32 + qsw];
#pragma unroll
        for (int j = 0; j < 2; ++j)
            wf[j] = *(const bf16x8*)&ksc[(wn + j * 16 + lm) * 32 + qsw];
#pragma unroll
        for (int i = 0; i < 4; ++i)
#pragma unroll
            for (int j = 0; j < 2; ++j)
                aB[i][j] = __builtin_amdgcn_mfma_f32_16x16x32_bf16(zf[i], wf[j], aB[i][j], 0, 0, 0);
#pragma unroll
        for (int j = 0; j < 2; ++j)
            wf[j] = *(const bf16x8*)&qsc[(wn + j * 16 + lm) * 32 + qsw];
#pragma unroll
        for (int i = 0; i < 4; ++i)
#pragma unroll
            for (int j = 0; j < 2; ++j)
                aC[i][j] = __builtin_amdgcn_mfma_f32_16x16x32_bf16(zf[i], wf[j], aC[i][j], 0, 0, 0);
#pragma unroll
        for (int j = 0; j < 2; ++j)
            wf[j] = *(const bf16x8*)&vsc[(wn + j * 16 + lm) * 32 + qsw];
#pragma unroll
        for (int i = 0; i < 4; ++i)
#pragma unroll
            for (int j = 0; j < 2; ++j)
                aV[i][j] = __builtin_amdgcn_mfma_f32_16x16x32_bf16(zf[i], wf[j], aV[i][j], 0, 0, 0);
        __syncthreads();
        cur ^= 1;
    }

    float dl[2];
#pragma unroll
    for (int j = 0; j < 2; ++j)
        dl[j] = softplusf_(delta_log[n0 + wn + j * 16 + lm]);

    // epilogue: write UC = u | c<<16 (one 4B store) + u fp32 to LDS for P
#pragma unroll
    for (int i = 0; i < 4; ++i) {
        const int lrow = wm + i * 16 + quad * 4;
        const int rbase = m0 + lrow;
#pragma unroll
        for (int j = 0; j < 2; ++j) {
            const int col = wn + j * 16 + lm;        // 0..63 within block
            const int gcol = n0 + col;
#pragma unroll
            for (int r = 0; r < 4; ++r) {
                const float uval = dl[j] * aB[i][j][r] * aV[i][j][r];
                const size_t idx = (size_t)(rbase + r) * Nn + gcol;
                UC[idx] = (unsigned)f2b(uval) | ((unsigned)f2b(aC[i][j][r]) << 16);
                uL[(lrow + r) * 66 + col] = uval;
            }
        }
    }
    __syncthreads();

    // chunk-local scan contribution P: 4 segments of 32 rows/col
    const int colp = tid & 63, seg = tid >> 6;
    const float a = sigmoidf_(a_logit[n0 + colp]);
    float l = 0.0f;
#pragma unroll 8
    for (int r = 0; r < 32; ++r)
        l = fmaf(a, l, uL[(seg * 32 + r) * 66 + colp]);
    pcomb[seg * 64 + colp] = l;
    __syncthreads();
    if (tid < 64) {
        float a32 = a;
#pragma unroll
        for (int i = 0; i < 5; ++i) a32 *= a32;      // a^32
        const float Pv = ((pcomb[tid] * a32 + pcomb[64 + tid]) * a32
                          + pcomb[128 + tid]) * a32 + pcomb[192 + tid];
        Pout[(size_t)blockIdx.x * Nn + n0 + tid] = Pv;
    }
}

// -------------------------------------------------------------------------
// Scan pass B: sequential over 32 chunks (fully unrolled); entry states + final.
// -------------------------------------------------------------------------
__global__ __launch_bounds__(256)
void scan_mid(const float* __restrict__ P, const float* __restrict__ state0,
              const float* __restrict__ a_logit,
              float* __restrict__ start, float* __restrict__ final_state)
{
    const int g = blockIdx.x * blockDim.x + threadIdx.x;
    const int n = g & (Nn - 1);
    const int b = g >> 8;
    const float a = sigmoidf_(a_logit[n]);
    float aL = a;
#pragma unroll
    for (int i = 0; i < 7; ++i) aL *= aL;   // a^128
    float s = state0[g];
#pragma unroll
    for (int ch = 0; ch < NCHK; ++ch) {
        const size_t idx = ((size_t)(b * NCHK + ch)) * Nn + n;
        start[idx] = s;
        s = fmaf(aL, s, P[idx]);
    }
    final_state[g] = s;
}

// -------------------------------------------------------------------------
// FUSED scan replay + G4 (R3 structure restored; UC interleave kept).
// grid dim3(2, 256): by = chunk (m-tile), bx = 512-col output half.
// 512 threads (8 waves), LDS 80 KB -> 2 blocks/CU, 16 waves/CU.
//   Phase 1: waves 0-1 (tid<128) replay the chunk scan from entry states
//            (one uint2 load per thread/step from interleaved UC), writing
//            ys bf16 into the 64 KB XOR-swizzled LDS tile; waves 4-7
//            meanwhile pre-stage the first out_proj tile (gl_lds16).
//   Phase 2: out[128 rows, 512 cols] = ys * OB^T; 4 n-subtiles x 8 k-phases,
//            flat 32-iter pipeline, dbuf Bs staged one phase ahead via
//            gl_lds16, one barrier per phase (R4 lesson: keep this pipeline).
// -------------------------------------------------------------------------
__global__ __launch_bounds__(512, 4)
void scan_g4_fused(const unsigned int* __restrict__ UC,
                   const float* __restrict__ start, const float* __restrict__ a_logit,
                   const unsigned short* __restrict__ OB, float* __restrict__ Out)
{
    __shared__ __align__(16) unsigned short ys[128 * 256];   // 64 KB, swizzled
    __shared__ __align__(16) unsigned short Bs[2][128 * 32]; // 2 x 8 KB
    const int tid = threadIdx.x;
    const int wave = tid >> 6, lane = tid & 63;
    const int hbase = blockIdx.x * 512;      // output column half
    const int m0 = blockIdx.y * 128;
    const int bidx = m0 >> 12;               // batch = m0 / Ss
    const int ch = (m0 & (Ss - 1)) >> 7;     // within-batch chunk
    const int quad = lane >> 4, lm = lane & 15;
    const int srow = lane >> 2;
    const int skoff = (((lane & 3) ^ ((srow >> 1) & 3)) << 3);   // pre-swizzled src (Bs)
    const int qsw = ((quad ^ ((lm >> 1) & 3)) << 3);             // swizzled read (Bs)

    // ---- phase 1: scan replay into LDS (waves 0-1), Bs[0] prestage (waves 4-7)
    if (tid < 128) {
        const int n = tid * 2;
        const float a0 = sigmoidf_(a_logit[n]);
        const float a1 = sigmoidf_(a_logit[n + 1]);
        const size_t sb = ((size_t)(bidx * NCHK + ch)) * Nn + n;
        float s0 = start[sb], s1 = start[sb + 1];
        size_t gb = ((size_t)m0) * Nn + n;   // index into UC (uint units)
        const int slot = n >> 3;             // 16B-slot of this col pair
        const int e = n & 7;                 // even -> 4B-aligned LDS store
#pragma unroll 8
        for (int t = 0; t < LCH; ++t) {
            const uint2 w = *(const uint2*)(UC + gb);
            s0 = fmaf(a0, s0, b2f((unsigned short)(w.x & 0xffffu)));
            s1 = fmaf(a1, s1, b2f((unsigned short)(w.y & 0xffffu)));
            const float y0 = b2f((unsigned short)(w.x >> 16)) * s0;
            const float y1 = b2f((unsigned short)(w.y >> 16)) * s1;
            *(unsigned*)&ys[t * 256 + (((slot ^ (t & 7)) << 3) + e)] =
                (unsigned)f2b(y0) | ((unsigned)f2b(y1) << 16);
            gb += Nn;
        }
    } else if (wave >= 4) {
        // prestage Bs[0]: regions 2(w-4), 2(w-4)+1 (rows of out_proj, k0=0)
#pragma unroll
        for (int q = 0; q < 2; ++q) {
            const int reg = 2 * (wave - 4) + q;
            gl_lds16(OB + (size_t)(hbase + reg * 16 + srow) * Nn + skoff, &Bs[0][reg * 512]);
        }
    }
    __syncthreads();

    // ---- phase 2: GEMM out[m0..+128, hbase..+512] = ys * OB^T
    // 8 waves as 2m x 4n: wave tile 64m x 32n.
    const int wm = (wave & 1) * 64, wn = (wave >> 1) * 32;
    f32x4 acc[4][2];

    for (int kk = 0; kk < 32; ++kk) {        // n0iter = kk>>3, k0 = (kk&7)*32
        const int buf = kk & 1;
        if ((kk & 7) == 0) {
#pragma unroll
            for (int i = 0; i < 4; ++i)
#pragma unroll
                for (int j = 0; j < 2; ++j)
                    acc[i][j] = (f32x4){0.f, 0.f, 0.f, 0.f};
        }
        if (kk + 1 < 32) {                   // stage next phase: wave w -> region w
            const int n0g = hbase + ((kk + 1) >> 3) * 128;
            const int k0n = ((kk + 1) & 7) * 32;
            gl_lds16(OB + (size_t)(n0g + wave * 16 + srow) * Nn + k0n + skoff,
                     &Bs[buf ^ 1][wave * 512]);
        }
        const int k0 = (kk & 7) * 32;
        const int c8 = (k0 >> 3) + quad;     // logical 16B-slot in ys row
        bf16x8 af[4], bfv[2];
#pragma unroll
        for (int i = 0; i < 4; ++i) {
            const int r = wm + i * 16 + lm;
            af[i] = *(const bf16x8*)&ys[r * 256 + ((c8 ^ (r & 7)) << 3)];
        }
#pragma unroll
        for (int j = 0; j < 2; ++j)
            bfv[j] = *(const bf16x8*)&Bs[buf][(wn + j * 16 + lm) * 32 + qsw];
#pragma unroll
        for (int i = 0; i < 4; ++i)
#pragma unroll
            for (int j = 0; j < 2; ++j)
                acc[i][j] = __builtin_amdgcn_mfma_f32_16x16x32_bf16(af[i], bfv[j], acc[i][j], 0, 0, 0);
        if ((kk & 7) == 7) {                 // epilogue for this 128-col subtile
            const int n0g = hbase + (kk >> 3) * 128;
#pragma unroll
            for (int i = 0; i < 4; ++i) {
                const int rbase = m0 + wm + i * 16 + quad * 4;
#pragma unroll
                for (int j = 0; j < 2; ++j) {
                    const int col = n0g + wn + j * 16 + lm;
#pragma unroll
                    for (int r = 0; r < 4; ++r)
                        Out[(size_t)(rbase + r) * Hh + col] = acc[i][j][r];
                }
            }
        }
        __syncthreads();
    }
}

// -------------------------------------------------------------------------
extern "C" void kernel_launch(void* const* d_in, const int* in_sizes, int n_in,
                              void* d_out, int out_size, void* d_ws, size_t ws_size,
                              hipStream_t stream)
{
    const float* x         = (const float*)d_in[0];
    const float* state0    = (const float*)d_in[1];
    const float* in_basis  = (const float*)d_in[2];
    const float* q_select  = (const float*)d_in[3];
    const float* k_select  = (const float*)d_in[4];
    const float* v_input   = (const float*)d_in[5];
    const float* out_proj  = (const float*)d_in[6];
    const float* a_logit   = (const float*)d_in[7];
    const float* delta_log = (const float*)d_in[8];

    float* out = (float*)d_out;
    float* final_state = out + (size_t)Mm * Hh;

    // workspace carve (~43.5 MB)
    char* ws = (char*)d_ws;
    unsigned int* uc   = (unsigned int*)ws;                      // 32 MB (u|c<<16)
    unsigned short* zb = (unsigned short*)(ws + 33554432);       // 8 MB
    unsigned short* ib = (unsigned short*)(ws + 41943040);       // 256 KB
    unsigned short* kb = (unsigned short*)(ws + 42205184);       // 64 KB
    unsigned short* qb = (unsigned short*)(ws + 42270720);       // 64 KB
    unsigned short* vb = (unsigned short*)(ws + 42336256);       // 64 KB
    unsigned short* ob = (unsigned short*)(ws + 42401792);       // 512 KB
    float* P  = (float*)(ws + 42926080);                         // 256 KB
    float* st = (float*)(ws + 43188224);                         // 256 KB

    cast_w<<<491520 / 256, 256, 0, stream>>>(in_basis, k_select, q_select, v_input, out_proj,
                                             ib, kb, qb, vb, ob);

    // G1: z = x * in_basis^T (fp32 x read directly, bf16 out)
    g1_fused<<<Mm / 64, 256, 0, stream>>>(x, ib, zb);

    // G2: uc (+ chunk contributions P) from z
    proj_mfma<<<dim3(Mm / 128, Nn / 64), 256, 0, stream>>>(zb, kb, qb, vb,
                                                           delta_log, a_logit, uc, P);

    // chunk-boundary scan (entry states per 128-chunk)
    scan_mid<<<(Bb * Nn) / 256, 256, 0, stream>>>(P, state0, a_logit, st, final_state);

    // fused: replay chunk scan in LDS + out = ys * out_proj^T (staged, dbuf)
    scan_g4_fused<<<dim3(2, Mm / 128), 512, 0, stream>>>(uc, st, a_logit, ob, out);
}